// Round 1
// baseline (3191.972 us; speedup 1.0000x reference)
//
#include <hip/hip_runtime.h>
#include <stdint.h>

#define Bb   8
#define Nn   8192
#define CIN  64
#define COUT 128
#define Mm   2048
#define KNN  16
#define NTOT (Bb*Nn)   // 65536 rows

// ---------------- ws layout (bytes) ----------------
// h        : [0,         33554432)   float 65536x128
// fps_idx  : [33554432,  33619968)   int   8x2048
// nbr      : [33619968,  35717120)   int   8x2048x16
// stats    : [35717120,  35718144)   float sum[128], sumsq[128]
// sb       : [35718144,  35719168)   float scale[128], bias[128]

// ============================================================
// FPS: one block per batch, 512 threads, 16 points/thread in regs.
// Distances computed with _rn intrinsics => bitwise-identical to numpy
// ((dx*dx+dy*dy)+dz*dz), argmax tie-break = lowest index.
// ============================================================
__global__ __launch_bounds__(512, 1)
void fps_kernel(const float* __restrict__ p1, int* __restrict__ fps_idx,
                float* __restrict__ p2out)
{
    __shared__ float px[Nn], py[Nn], pz[Nn];
    __shared__ unsigned long long wkey[8];
    const int b   = blockIdx.x;
    const int tid = threadIdx.x;
    const float* pb = p1 + b * Nn * 3;

    for (int i = tid; i < Nn * 3; i += 512) {
        float v = pb[i];
        int pt = i / 3;
        int c  = i - pt * 3;
        if (c == 0) px[pt] = v; else if (c == 1) py[pt] = v; else pz[pt] = v;
    }
    __syncthreads();

    float ppx[16], ppy[16], ppz[16], mind[16];
#pragma unroll
    for (int i = 0; i < 16; ++i) {
        int j = tid + (i << 9);
        ppx[i] = px[j]; ppy[i] = py[j]; ppz[i] = pz[j];
        mind[i] = 1e10f;
    }

    float lx = px[0], ly = py[0], lz = pz[0];
    if (tid == 0) {
        fps_idx[b * Mm] = 0;
        int o = (b * Mm) * 3;
        p2out[o] = lx; p2out[o + 1] = ly; p2out[o + 2] = lz;
    }

    const int lane = tid & 63, wid = tid >> 6;

    for (int m = 1; m < Mm; ++m) {
        float bestv = -1.0f; int bestj = 0;
#pragma unroll
        for (int i = 0; i < 16; ++i) {
            float dx = __fsub_rn(ppx[i], lx);
            float dy = __fsub_rn(ppy[i], ly);
            float dz = __fsub_rn(ppz[i], lz);
            float d  = __fadd_rn(__fadd_rn(__fmul_rn(dx, dx), __fmul_rn(dy, dy)),
                                 __fmul_rn(dz, dz));
            float mv = fminf(mind[i], d);
            mind[i] = mv;
            if (mv > bestv) { bestv = mv; bestj = tid + (i << 9); }
        }
        // pack: larger dist wins; tie -> smaller index (via ~j)
        unsigned long long key =
            ((unsigned long long)__float_as_uint(bestv) << 32) |
            (unsigned int)(~(unsigned int)bestj);
#pragma unroll
        for (int off = 1; off < 64; off <<= 1) {
            unsigned long long ok = __shfl_xor(key, off, 64);
            key = ok > key ? ok : key;
        }
        if (lane == 0) wkey[wid] = key;
        __syncthreads();
        unsigned long long fk = wkey[0];
#pragma unroll
        for (int w = 1; w < 8; ++w) {
            unsigned long long ok = wkey[w];
            fk = ok > fk ? ok : fk;
        }
        int lastIdx = (int)(~(unsigned int)fk);
        lx = px[lastIdx]; ly = py[lastIdx]; lz = pz[lastIdx];
        if (tid == 0) {
            fps_idx[b * Mm + m] = lastIdx;
            int o = (b * Mm + m) * 3;
            p2out[o] = lx; p2out[o + 1] = ly; p2out[o + 2] = lz;
        }
        __syncthreads();
    }
}

// ============================================================
// kNN top-16: one wave per query (16 queries/block), p1 staged in LDS.
// d2 = (|q|^2 - 2*dot) + |p|^2 exactly as reference; sortable u64 keys
// (sortbits(d2)<<32 | j) so ties break by lower index like lax.top_k.
// Per-lane top-2 cache + wave min-reduce; rare rescan on double-win.
// ============================================================
__device__ __forceinline__ unsigned long long d2key(
    float qx, float qy, float qz, float qn, float x, float y, float z, int j)
{
    float dot = __fadd_rn(__fadd_rn(__fmul_rn(qx, x), __fmul_rn(qy, y)),
                          __fmul_rn(qz, z));
    float cn  = __fadd_rn(__fadd_rn(__fmul_rn(x, x), __fmul_rn(y, y)),
                          __fmul_rn(z, z));
    float d2  = __fadd_rn(__fsub_rn(qn, __fadd_rn(dot, dot)), cn);
    unsigned int bits = __float_as_uint(d2);
    unsigned int u = bits ^ (((unsigned int)((int)bits >> 31)) | 0x80000000u);
    return ((unsigned long long)u << 32) | (unsigned int)j;
}

__global__ __launch_bounds__(1024, 1)
void topk_kernel(const float* __restrict__ p1, const float* __restrict__ p2o,
                 int* __restrict__ nbr)
{
    __shared__ float px[Nn], py[Nn], pz[Nn];
    const int tid = threadIdx.x;
    const int b     = blockIdx.x >> 7;
    const int mbase = (blockIdx.x & 127) << 4;
    const float* pb = p1 + b * Nn * 3;

    for (int i = tid; i < Nn * 3; i += 1024) {
        float v = pb[i];
        int pt = i / 3;
        int c  = i - pt * 3;
        if (c == 0) px[pt] = v; else if (c == 1) py[pt] = v; else pz[pt] = v;
    }
    __syncthreads();

    const int wid = tid >> 6, lane = tid & 63;
    const int m = mbase + wid;
    const int qrow = b * Mm + m;
    float qx = p2o[qrow * 3], qy = p2o[qrow * 3 + 1], qz = p2o[qrow * 3 + 2];
    float qn = __fadd_rn(__fadd_rn(__fmul_rn(qx, qx), __fmul_rn(qy, qy)),
                         __fmul_rn(qz, qz));

    const unsigned long long INV = ~0ull;
    unsigned long long k1 = INV, k2 = INV;
#pragma unroll 4
    for (int i = 0; i < 128; ++i) {
        int j = lane + (i << 6);
        unsigned long long key = d2key(qx, qy, qz, qn, px[j], py[j], pz[j], j);
        if (key < k1) { k2 = k1; k1 = key; }
        else if (key < k2) { k2 = key; }
    }

    int* out = nbr + qrow * KNN;
    for (int r = 0; r < KNN; ++r) {
        unsigned long long wk = k1;
#pragma unroll
        for (int off = 1; off < 64; off <<= 1) {
            unsigned long long ok = __shfl_xor(wk, off, 64);
            wk = ok < wk ? ok : wk;
        }
        if (lane == 0) out[r] = (int)(unsigned int)(wk & 0xFFFFFFFFull);
        if (k1 == wk) { k1 = k2; k2 = INV; }
        if (k1 == INV) {   // rare: this lane's cache exhausted -> rescan
            for (int i = 0; i < 128; ++i) {
                int j = lane + (i << 6);
                unsigned long long key =
                    d2key(qx, qy, qz, qn, px[j], py[j], pz[j], j);
                if (key > wk) {
                    if (key < k1) { k2 = k1; k1 = key; }
                    else if (key < k2) { k2 = key; }
                }
            }
        }
    }
}

// ============================================================
// h = x @ W^T : wave per row, lane = channel pair. x loads are
// wave-uniform (broadcast); W stays hot in L1 (32 KB).
// ============================================================
__global__ __launch_bounds__(256)
void gemm_kernel(const float* __restrict__ x, const float* __restrict__ W,
                 float* __restrict__ h)
{
    const int r  = blockIdx.x * 4 + (threadIdx.x >> 6);
    const int cp = threadIdx.x & 63;
    const float4* xr = (const float4*)(x + r * CIN);
    const float4* w0 = (const float4*)(W + (cp * 2) * CIN);
    const float4* w1 = (const float4*)(W + (cp * 2 + 1) * CIN);
    float a0 = 0.f, a1 = 0.f;
#pragma unroll
    for (int k = 0; k < CIN / 4; ++k) {
        float4 xv = xr[k], wa = w0[k], wb = w1[k];
        a0 = fmaf(xv.x, wa.x, fmaf(xv.y, wa.y, fmaf(xv.z, wa.z, fmaf(xv.w, wa.w, a0))));
        a1 = fmaf(xv.x, wb.x, fmaf(xv.y, wb.y, fmaf(xv.z, wb.z, fmaf(xv.w, wb.w, a1))));
    }
    float2* ho = (float2*)(h + r * COUT + cp * 2);
    *ho = make_float2(a0, a1);
}

// ============================================================
// BN stats: per-channel sum & sumsq over 65536 rows.
// ============================================================
__global__ __launch_bounds__(256)
void stats_kernel(const float* __restrict__ h, float* __restrict__ stats)
{
    __shared__ float4 rs[256], rq[256];
    const int tid  = threadIdx.x;
    const int c4   = (tid & 31) * 4;
    const int rsub = tid >> 5;
    const int rbase = blockIdx.x * 256;
    float4 s = make_float4(0, 0, 0, 0), q = make_float4(0, 0, 0, 0);
    for (int i = 0; i < 32; ++i) {
        int r = rbase + rsub + i * 8;
        float4 v = *(const float4*)(h + r * COUT + c4);
        s.x += v.x; s.y += v.y; s.z += v.z; s.w += v.w;
        q.x = fmaf(v.x, v.x, q.x); q.y = fmaf(v.y, v.y, q.y);
        q.z = fmaf(v.z, v.z, q.z); q.w = fmaf(v.w, v.w, q.w);
    }
    rs[tid] = s; rq[tid] = q;
    __syncthreads();
    if (tid < 32) {
        for (int j = 1; j < 8; ++j) {
            float4 o = rs[tid + 32 * j];
            s.x += o.x; s.y += o.y; s.z += o.z; s.w += o.w;
            float4 oq = rq[tid + 32 * j];
            q.x += oq.x; q.y += oq.y; q.z += oq.z; q.w += oq.w;
        }
        atomicAdd(&stats[c4 + 0], s.x); atomicAdd(&stats[c4 + 1], s.y);
        atomicAdd(&stats[c4 + 2], s.z); atomicAdd(&stats[c4 + 3], s.w);
        atomicAdd(&stats[128 + c4 + 0], q.x); atomicAdd(&stats[128 + c4 + 1], q.y);
        atomicAdd(&stats[128 + c4 + 2], q.z); atomicAdd(&stats[128 + c4 + 3], q.w);
    }
}

__global__ void finalize_kernel(const float* __restrict__ stats,
                                const float* __restrict__ gamma,
                                const float* __restrict__ beta,
                                float* __restrict__ sb)
{
    int c = threadIdx.x;
    float mean = stats[c] * (1.0f / 65536.0f);
    float var  = stats[128 + c] * (1.0f / 65536.0f) - mean * mean;
    float scale = gamma[c] / sqrtf(var + 1e-5f);
    float bias  = beta[c] - mean * scale;
    sb[c] = scale; sb[128 + c] = bias;
}

// ============================================================
// Gather + BN affine + ReLU + max over K. One wave per (b,m),
// lane = channel pair. relu(max(.)) == max(relu(.)) (monotone).
// ============================================================
__global__ __launch_bounds__(256)
void gather_kernel(const float* __restrict__ h, const int* __restrict__ nbr,
                   const float* __restrict__ sb, float* __restrict__ y)
{
    const int wid = threadIdx.x >> 6, lane = threadIdx.x & 63;
    const int t4 = blockIdx.x * 4 + wid;    // == b*2048 + m
    const int b  = t4 >> 11;
    const int c0 = lane * 2;
    float s0 = sb[c0], s1 = sb[c0 + 1];
    float b0 = sb[128 + c0], b1 = sb[128 + c0 + 1];
    const int* nb = nbr + t4 * KNN;
    float a0 = -1e30f, a1 = -1e30f;
#pragma unroll
    for (int k = 0; k < KNN; ++k) {
        int idx = nb[k];
        float2 v = *(const float2*)(h + ((b << 13) + idx) * COUT + c0);
        a0 = fmaxf(a0, fmaf(v.x, s0, b0));
        a1 = fmaxf(a1, fmaf(v.y, s1, b1));
    }
    a0 = fmaxf(a0, 0.0f); a1 = fmaxf(a1, 0.0f);
    *(float2*)(y + t4 * COUT + c0) = make_float2(a0, a1);
}

extern "C" void kernel_launch(void* const* d_in, const int* in_sizes, int n_in,
                              void* d_out, int out_size, void* d_ws, size_t ws_size,
                              hipStream_t stream)
{
    const float* x     = (const float*)d_in[0];
    const float* p1    = (const float*)d_in[1];
    const float* W     = (const float*)d_in[2];
    const float* gamma = (const float*)d_in[3];
    const float* beta  = (const float*)d_in[4];

    float* y  = (float*)d_out;                       // (8,2048,128)
    float* p2 = (float*)d_out + Bb * Mm * COUT;      // (8,2048,3)

    char*  ws      = (char*)d_ws;
    float* h       = (float*)ws;
    int*   fps_idx = (int*)(ws + 33554432);
    int*   nbr     = (int*)(ws + 33619968);
    float* stats   = (float*)(ws + 35717120);
    float* sb      = (float*)(ws + 35718144);

    hipMemsetAsync(stats, 0, 1024, stream);
    fps_kernel<<<Bb, 512, 0, stream>>>(p1, fps_idx, p2);
    gemm_kernel<<<NTOT / 4, 256, 0, stream>>>(x, W, h);
    stats_kernel<<<256, 256, 0, stream>>>(h, stats);
    finalize_kernel<<<1, 128, 0, stream>>>(stats, gamma, beta, sb);
    topk_kernel<<<Bb * 128, 1024, 0, stream>>>(p1, p2, nbr);
    gather_kernel<<<Bb * Mm / 4, 256, 0, stream>>>(h, nbr, sb, y);
}

// Round 5
// 2835.005 us; speedup vs baseline: 1.1259x; 1.1259x over previous
//
#include <hip/hip_runtime.h>
#include <stdint.h>

#define Bb   8
#define Nn   8192
#define CIN  64
#define COUT 128
#define Mm   2048
#define KNN  16
#define NTOT (Bb*Nn)   // 65536 rows

typedef unsigned long long ull;

// ---------------- ws layout (bytes) ----------------
// h        : [0,         33554432)   float 65536x128
// fps_idx  : [33554432,  33619968)   int   8x2048
// nbr      : [33619968,  35717120)   int   8x2048x16
// stats    : [35717120,  35718144)   float sum[128], sumsq[128]
// sb       : [35718144,  35719168)   float scale[128], bias[128]
//
// LDS RULE (R2-R4 lesson): every workgroup's static LDS must stay
// <= 98,816 B (the largest size empirically proven to launch, R1).
// 131,072 B (and 131,200 B) silently failed to launch -> poison
// outputs. Keep all kernels on 3-plane float[8192] layouts.

// ============================================================
// FPS — R1 VERBATIM (empirically proven, 2395 us). One block per
// batch, 512 threads, 16 pts/thread strided. _rn intrinsics give
// bitwise numpy-identical ((dx^2+dy^2)+dz^2); u64 key argmax with
// ~j tie-break = lowest index. Two barriers per iteration.
// ============================================================
__global__ __launch_bounds__(512, 1)
void fps_kernel(const float* __restrict__ p1, int* __restrict__ fps_idx,
                float* __restrict__ p2out)
{
    __shared__ float px[Nn], py[Nn], pz[Nn];   // 96 KB
    __shared__ ull wkey[8];
    const int b   = blockIdx.x;
    const int tid = threadIdx.x;
    const float* pb = p1 + b * Nn * 3;

    for (int i = tid; i < Nn * 3; i += 512) {
        float v = pb[i];
        int pt = i / 3;
        int c  = i - pt * 3;
        if (c == 0) px[pt] = v; else if (c == 1) py[pt] = v; else pz[pt] = v;
    }
    __syncthreads();

    float ppx[16], ppy[16], ppz[16], mind[16];
#pragma unroll
    for (int i = 0; i < 16; ++i) {
        int j = tid + (i << 9);
        ppx[i] = px[j]; ppy[i] = py[j]; ppz[i] = pz[j];
        mind[i] = 1e10f;
    }

    float lx = px[0], ly = py[0], lz = pz[0];
    if (tid == 0) {
        fps_idx[b * Mm] = 0;
        int o = (b * Mm) * 3;
        p2out[o] = lx; p2out[o + 1] = ly; p2out[o + 2] = lz;
    }

    const int lane = tid & 63, wid = tid >> 6;

    for (int m = 1; m < Mm; ++m) {
        float bestv = -1.0f; int bestj = 0;
#pragma unroll
        for (int i = 0; i < 16; ++i) {
            float dx = __fsub_rn(ppx[i], lx);
            float dy = __fsub_rn(ppy[i], ly);
            float dz = __fsub_rn(ppz[i], lz);
            float d  = __fadd_rn(__fadd_rn(__fmul_rn(dx, dx), __fmul_rn(dy, dy)),
                                 __fmul_rn(dz, dz));
            float mv = fminf(mind[i], d);
            mind[i] = mv;
            if (mv > bestv) { bestv = mv; bestj = tid + (i << 9); }
        }
        ull key = ((ull)__float_as_uint(bestv) << 32) |
                  (unsigned int)(~(unsigned int)bestj);
#pragma unroll
        for (int off = 1; off < 64; off <<= 1) {
            ull ok = __shfl_xor(key, off, 64);
            key = ok > key ? ok : key;
        }
        if (lane == 0) wkey[wid] = key;
        __syncthreads();
        ull fk = wkey[0];
#pragma unroll
        for (int w = 1; w < 8; ++w) {
            ull ok = wkey[w];
            fk = ok > fk ? ok : fk;
        }
        int lastIdx = (int)(~(unsigned int)fk);
        lx = px[lastIdx]; ly = py[lastIdx]; lz = pz[lastIdx];
        if (tid == 0) {
            fps_idx[b * Mm + m] = lastIdx;
            int o = (b * Mm + m) * 3;
            p2out[o] = lx; p2out[o + 1] = ly; p2out[o + 2] = lz;
        }
        __syncthreads();
    }
}

// ============================================================
// kNN top-16: one wave per query (16 queries/block). LDS = R1's
// proven 3-plane layout (98,304 B; |p|^2 computed in-loop with
// R1's exact _rn sequence). NEW vs R1: per-lane branchless top-3
// register cache (rescan prob ~0.14/wave vs ~1.9 for top-2).
// Sortable u64 keys tie-break lower index like lax.top_k.
// ============================================================
__device__ __forceinline__ ull d2key(
    float qx, float qy, float qz, float qn, float x, float y, float z, int j)
{
    float dot = __fadd_rn(__fadd_rn(__fmul_rn(qx, x), __fmul_rn(qy, y)),
                          __fmul_rn(qz, z));
    float cn  = __fadd_rn(__fadd_rn(__fmul_rn(x, x), __fmul_rn(y, y)),
                          __fmul_rn(z, z));
    float d2  = __fadd_rn(__fsub_rn(qn, __fadd_rn(dot, dot)), cn);
    unsigned int bits = __float_as_uint(d2);
    unsigned int u = bits ^ (((unsigned int)((int)bits >> 31)) | 0x80000000u);
    return ((ull)u << 32) | (unsigned int)j;
}

__global__ __launch_bounds__(1024, 1)
void topk_kernel(const float* __restrict__ p1, const float* __restrict__ p2o,
                 int* __restrict__ nbr)
{
    __shared__ float px[Nn], py[Nn], pz[Nn];   // 96 KB
    const int tid   = threadIdx.x;
    const int b     = blockIdx.x >> 7;
    const int mbase = (blockIdx.x & 127) << 4;
    const float* pb = p1 + b * Nn * 3;

    for (int i = tid; i < Nn * 3; i += 1024) {
        float v = pb[i];
        int pt = i / 3;
        int c  = i - pt * 3;
        if (c == 0) px[pt] = v; else if (c == 1) py[pt] = v; else pz[pt] = v;
    }
    __syncthreads();

    const int wid = tid >> 6, lane = tid & 63;
    const int qrow = b * Mm + mbase + wid;
    float qx = p2o[qrow * 3], qy = p2o[qrow * 3 + 1], qz = p2o[qrow * 3 + 2];
    float qn = __fadd_rn(__fadd_rn(__fmul_rn(qx, qx), __fmul_rn(qy, qy)),
                         __fmul_rn(qz, qz));

    const ull INV = ~0ull;
    ull k1 = INV, k2 = INV, k3 = INV;
#pragma unroll 4
    for (int i = 0; i < 128; ++i) {
        int j = lane + (i << 6);
        ull key = d2key(qx, qy, qz, qn, px[j], py[j], pz[j], j);
        bool b1 = key < k1, b2 = key < k2, b3 = key < k3;
        ull n1 = b1 ? key : k1;
        ull n2 = b1 ? k1 : (b2 ? key : k2);
        ull n3 = b2 ? k2 : (b3 ? key : k3);
        k1 = n1; k2 = n2; k3 = n3;
    }

    int* out = nbr + qrow * KNN;
    for (int r = 0; r < KNN; ++r) {
        ull wk = k1;
#pragma unroll
        for (int off = 1; off < 64; off <<= 1) {
            ull ok = __shfl_xor(wk, off, 64);
            wk = ok < wk ? ok : wk;
        }
        if (lane == 0) out[r] = (int)(unsigned int)(wk & 0xFFFFFFFFull);
        if (k1 == wk) { k1 = k2; k2 = k3; k3 = INV; }
        if (k1 == INV) {   // rare: rebuild top-3 among keys > wk
            for (int i = 0; i < 128; ++i) {
                int j = lane + (i << 6);
                ull key = d2key(qx, qy, qz, qn, px[j], py[j], pz[j], j);
                if (key > wk) {
                    bool b1 = key < k1, b2 = key < k2, b3 = key < k3;
                    ull n1 = b1 ? key : k1;
                    ull n2 = b1 ? k1 : (b2 ? key : k2);
                    ull n3 = b2 ? k2 : (b3 ? key : k3);
                    k1 = n1; k2 = n2; k3 = n3;
                }
            }
        }
    }
}

// ============================================================
// h = x @ W^T : 4 rows per wave (amortizes W loads 4x). No LDS.
// Identical fmaf chains per element as the R1-proven kernel.
// ============================================================
__global__ __launch_bounds__(256)
void gemm_kernel(const float* __restrict__ x, const float* __restrict__ W,
                 float* __restrict__ h)
{
    const int r0 = blockIdx.x * 16 + (threadIdx.x >> 6) * 4;
    const int cp = threadIdx.x & 63;
    const float4* xp = (const float4*)(x + r0 * CIN);
    const float4* w0 = (const float4*)(W + (cp * 2) * CIN);
    const float4* w1 = (const float4*)(W + (cp * 2 + 1) * CIN);
    float a[4][2];
#pragma unroll
    for (int r = 0; r < 4; ++r) { a[r][0] = 0.f; a[r][1] = 0.f; }
#pragma unroll
    for (int k = 0; k < CIN / 4; ++k) {
        float4 wa = w0[k], wb = w1[k];
#pragma unroll
        for (int r = 0; r < 4; ++r) {
            float4 xv = xp[r * 16 + k];
            a[r][0] = fmaf(xv.x, wa.x, fmaf(xv.y, wa.y, fmaf(xv.z, wa.z, fmaf(xv.w, wa.w, a[r][0]))));
            a[r][1] = fmaf(xv.x, wb.x, fmaf(xv.y, wb.y, fmaf(xv.z, wb.z, fmaf(xv.w, wb.w, a[r][1]))));
        }
    }
#pragma unroll
    for (int r = 0; r < 4; ++r)
        *(float2*)(h + (r0 + r) * COUT + cp * 2) = make_float2(a[r][0], a[r][1]);
}

// ============================================================
// BN stats: per-channel sum & sumsq over 65536 rows. (R1 verbatim)
// ============================================================
__global__ __launch_bounds__(256)
void stats_kernel(const float* __restrict__ h, float* __restrict__ stats)
{
    __shared__ float4 rs[256], rq[256];
    const int tid  = threadIdx.x;
    const int c4   = (tid & 31) * 4;
    const int rsub = tid >> 5;
    const int rbase = blockIdx.x * 256;
    float4 s = make_float4(0, 0, 0, 0), q = make_float4(0, 0, 0, 0);
    for (int i = 0; i < 32; ++i) {
        int r = rbase + rsub + i * 8;
        float4 v = *(const float4*)(h + r * COUT + c4);
        s.x += v.x; s.y += v.y; s.z += v.z; s.w += v.w;
        q.x = fmaf(v.x, v.x, q.x); q.y = fmaf(v.y, v.y, q.y);
        q.z = fmaf(v.z, v.z, q.z); q.w = fmaf(v.w, v.w, q.w);
    }
    rs[tid] = s; rq[tid] = q;
    __syncthreads();
    if (tid < 32) {
        for (int j = 1; j < 8; ++j) {
            float4 o = rs[tid + 32 * j];
            s.x += o.x; s.y += o.y; s.z += o.z; s.w += o.w;
            float4 oq = rq[tid + 32 * j];
            q.x += oq.x; q.y += oq.y; q.z += oq.z; q.w += oq.w;
        }
        atomicAdd(&stats[c4 + 0], s.x); atomicAdd(&stats[c4 + 1], s.y);
        atomicAdd(&stats[c4 + 2], s.z); atomicAdd(&stats[c4 + 3], s.w);
        atomicAdd(&stats[128 + c4 + 0], q.x); atomicAdd(&stats[128 + c4 + 1], q.y);
        atomicAdd(&stats[128 + c4 + 2], q.z); atomicAdd(&stats[128 + c4 + 3], q.w);
    }
}

__global__ void finalize_kernel(const float* __restrict__ stats,
                                const float* __restrict__ gamma,
                                const float* __restrict__ beta,
                                float* __restrict__ sb)
{
    int c = threadIdx.x;
    float mean = stats[c] * (1.0f / 65536.0f);
    float var  = stats[128 + c] * (1.0f / 65536.0f) - mean * mean;
    float scale = gamma[c] / sqrtf(var + 1e-5f);
    float bias  = beta[c] - mean * scale;
    sb[c] = scale; sb[128 + c] = bias;
}

// ============================================================
// Gather + BN affine + ReLU + max over K. (R1 verbatim)
// ============================================================
__global__ __launch_bounds__(256)
void gather_kernel(const float* __restrict__ h, const int* __restrict__ nbr,
                   const float* __restrict__ sb, float* __restrict__ y)
{
    const int wid = threadIdx.x >> 6, lane = threadIdx.x & 63;
    const int t4 = blockIdx.x * 4 + wid;    // == b*2048 + m
    const int b  = t4 >> 11;
    const int c0 = lane * 2;
    float s0 = sb[c0], s1 = sb[c0 + 1];
    float b0 = sb[128 + c0], b1 = sb[128 + c0 + 1];
    const int* nb = nbr + t4 * KNN;
    float a0 = -1e30f, a1 = -1e30f;
#pragma unroll
    for (int k = 0; k < KNN; ++k) {
        int idx = nb[k];
        float2 v = *(const float2*)(h + ((b << 13) + idx) * COUT + c0);
        a0 = fmaxf(a0, fmaf(v.x, s0, b0));
        a1 = fmaxf(a1, fmaf(v.y, s1, b1));
    }
    a0 = fmaxf(a0, 0.0f); a1 = fmaxf(a1, 0.0f);
    *(float2*)(y + t4 * COUT + c0) = make_float2(a0, a1);
}

extern "C" void kernel_launch(void* const* d_in, const int* in_sizes, int n_in,
                              void* d_out, int out_size, void* d_ws, size_t ws_size,
                              hipStream_t stream)
{
    const float* x     = (const float*)d_in[0];
    const float* p1    = (const float*)d_in[1];
    const float* W     = (const float*)d_in[2];
    const float* gamma = (const float*)d_in[3];
    const float* beta  = (const float*)d_in[4];

    float* y  = (float*)d_out;                       // (8,2048,128)
    float* p2 = (float*)d_out + Bb * Mm * COUT;      // (8,2048,3)

    char*  ws      = (char*)d_ws;
    float* h       = (float*)ws;
    int*   fps_idx = (int*)(ws + 33554432);
    int*   nbr     = (int*)(ws + 33619968);
    float* stats   = (float*)(ws + 35717120);
    float* sb      = (float*)(ws + 35718144);

    hipMemsetAsync(stats, 0, 1024, stream);
    fps_kernel<<<Bb, 512, 0, stream>>>(p1, fps_idx, p2);
    gemm_kernel<<<NTOT / 16, 256, 0, stream>>>(x, W, h);
    stats_kernel<<<256, 256, 0, stream>>>(h, stats);
    finalize_kernel<<<1, 128, 0, stream>>>(stats, gamma, beta, sb);
    topk_kernel<<<Bb * 128, 1024, 0, stream>>>(p1, p2, nbr);
    gather_kernel<<<Bb * Mm / 4, 256, 0, stream>>>(h, nbr, sb, y);
}

// Round 6
// 2328.935 us; speedup vs baseline: 1.3706x; 1.2173x over previous
//
#include <hip/hip_runtime.h>
#include <stdint.h>

#define Bb   8
#define Nn   8192
#define CIN  64
#define COUT 128
#define Mm   2048
#define KNN  16
#define NTOT (Bb*Nn)   // 65536 rows

typedef unsigned long long ull;

// ---------------- ws layout (bytes) ----------------
// h        : [0,         33554432)   float 65536x128
// nbr      : [33619968,  35717120)   int   8x2048x16
// stats    : [35717120,  35718144)   float sum[128], sumsq[128]
// sb       : [35718144,  35719168)   float scale[128], bias[128]
//
// LDS RULE (R2-R4 lesson): every workgroup's static LDS must stay
// <= 98,816 B. 131,072+ B silently fails to launch -> poison.

// ============================================================
// Wave64 float-max reduce: 4x DPP row_shr within 16-lane rows
// (old=self => out-of-row lanes keep own value; max idempotent),
// then v_readlane of lanes 15/31/47/63 + uniform u32 max (valid
// for our values: all distances >= 0, no -0/NaN). ~50 cyc vs
// ~600 for the u64 ds_bpermute butterfly.
// ============================================================
__device__ __forceinline__ float wave_max16(float x)
{
    int v = __float_as_int(x), t;
    t = __builtin_amdgcn_update_dpp(v, v, 0x111, 0xf, 0xf, false); // row_shr:1
    v = __float_as_int(fmaxf(__int_as_float(v), __int_as_float(t)));
    t = __builtin_amdgcn_update_dpp(v, v, 0x112, 0xf, 0xf, false); // row_shr:2
    v = __float_as_int(fmaxf(__int_as_float(v), __int_as_float(t)));
    t = __builtin_amdgcn_update_dpp(v, v, 0x114, 0xf, 0xf, false); // row_shr:4
    v = __float_as_int(fmaxf(__int_as_float(v), __int_as_float(t)));
    t = __builtin_amdgcn_update_dpp(v, v, 0x118, 0xf, 0xf, false); // row_shr:8
    v = __float_as_int(fmaxf(__int_as_float(v), __int_as_float(t)));
    unsigned r0 = (unsigned)__builtin_amdgcn_readlane(v, 15);
    unsigned r1 = (unsigned)__builtin_amdgcn_readlane(v, 31);
    unsigned r2 = (unsigned)__builtin_amdgcn_readlane(v, 47);
    unsigned r3 = (unsigned)__builtin_amdgcn_readlane(v, 63);
    unsigned m0 = r0 > r1 ? r0 : r1;
    unsigned m1 = r2 > r3 ? r2 : r3;
    unsigned mm = m0 > m1 ? m0 : m1;
    return __uint_as_float(mm);
}

// ============================================================
// FPS: one block per batch, 512 threads, 16 pts/thread BLOCKED
// (thread t owns j in [16t,16t+16) so lane order == index order;
// strict > keeps lowest i within a thread => ballot lowest-lane
// == lowest tying index; ~j in the cross-wave u64 key finishes
// global tie-break). Distance math: proven _rn sequence, bitwise
// numpy-identical ((dx^2+dy^2)+dz^2). DPP wave max + ballot,
// ONE double-buffered barrier per iteration (was 2 + butterfly).
// ============================================================
__global__ __launch_bounds__(512, 1)
void fps_kernel(const float* __restrict__ p1, float* __restrict__ p2out)
{
    __shared__ float px[Nn], py[Nn], pz[Nn];   // 96 KB
    __shared__ ull   wkey[2][8];
    const int b    = blockIdx.x;
    const int tid  = threadIdx.x;
    const int lane = tid & 63, wid = tid >> 6;
    const float* pb = p1 + b * Nn * 3;

    for (int i = tid; i < Nn * 3; i += 512) {
        float v = pb[i];
        int pt = i / 3;
        int c  = i - pt * 3;
        if (c == 0) px[pt] = v; else if (c == 1) py[pt] = v; else pz[pt] = v;
    }
    __syncthreads();

    float ppx[16], ppy[16], ppz[16], mind[16];
#pragma unroll
    for (int i = 0; i < 16; ++i) {
        int j = tid * 16 + i;                  // blocked mapping
        ppx[i] = px[j]; ppy[i] = py[j]; ppz[i] = pz[j];
        mind[i] = 1e10f;
    }

    float lx = px[0], ly = py[0], lz = pz[0];
    if (tid == 0) {
        int o = (b * Mm) * 3;
        p2out[o] = lx; p2out[o + 1] = ly; p2out[o + 2] = lz;
    }

    for (int m = 1; m < Mm; ++m) {
        const int buf = m & 1;
        float bestv = -1.0f; int bestj = 0;
#pragma unroll
        for (int i = 0; i < 16; ++i) {
            float dx = __fsub_rn(ppx[i], lx);
            float dy = __fsub_rn(ppy[i], ly);
            float dz = __fsub_rn(ppz[i], lz);
            float d  = __fadd_rn(__fadd_rn(__fmul_rn(dx, dx), __fmul_rn(dy, dy)),
                                 __fmul_rn(dz, dz));
            float mv = fminf(mind[i], d);
            mind[i] = mv;
            if (mv > bestv) { bestv = mv; bestj = tid * 16 + i; }
        }

        float wv = wave_max16(bestv);
        ull tie = __ballot(bestv == wv);
        int low = __ffsll((long long)tie) - 1;   // lowest lane = lowest index
        if (lane == low) {
            wkey[buf][wid] = ((ull)__float_as_uint(wv) << 32) |
                             (unsigned int)(~(unsigned int)bestj);
        }
        __syncthreads();

        ull fk = wkey[buf][0];
#pragma unroll
        for (int w = 1; w < 8; ++w) { ull k = wkey[buf][w]; fk = k > fk ? k : fk; }
        int jw = (int)(~(unsigned int)fk);
        lx = px[jw]; ly = py[jw]; lz = pz[jw];   // broadcast reads
        if (tid == 0) {
            int o = (b * Mm + m) * 3;
            p2out[o] = lx; p2out[o + 1] = ly; p2out[o + 2] = lz;
        }
    }
}

// ============================================================
// kNN top-16 (R5 verbatim, passing): one wave per query, 3-plane
// LDS (98,304 B), per-lane branchless top-3 cache, sortable u64
// keys tie-break lower index like lax.top_k.
// ============================================================
__device__ __forceinline__ ull d2key(
    float qx, float qy, float qz, float qn, float x, float y, float z, int j)
{
    float dot = __fadd_rn(__fadd_rn(__fmul_rn(qx, x), __fmul_rn(qy, y)),
                          __fmul_rn(qz, z));
    float cn  = __fadd_rn(__fadd_rn(__fmul_rn(x, x), __fmul_rn(y, y)),
                          __fmul_rn(z, z));
    float d2  = __fadd_rn(__fsub_rn(qn, __fadd_rn(dot, dot)), cn);
    unsigned int bits = __float_as_uint(d2);
    unsigned int u = bits ^ (((unsigned int)((int)bits >> 31)) | 0x80000000u);
    return ((ull)u << 32) | (unsigned int)j;
}

__global__ __launch_bounds__(1024, 1)
void topk_kernel(const float* __restrict__ p1, const float* __restrict__ p2o,
                 int* __restrict__ nbr)
{
    __shared__ float px[Nn], py[Nn], pz[Nn];   // 96 KB
    const int tid   = threadIdx.x;
    const int b     = blockIdx.x >> 7;
    const int mbase = (blockIdx.x & 127) << 4;
    const float* pb = p1 + b * Nn * 3;

    for (int i = tid; i < Nn * 3; i += 1024) {
        float v = pb[i];
        int pt = i / 3;
        int c  = i - pt * 3;
        if (c == 0) px[pt] = v; else if (c == 1) py[pt] = v; else pz[pt] = v;
    }
    __syncthreads();

    const int wid = tid >> 6, lane = tid & 63;
    const int qrow = b * Mm + mbase + wid;
    float qx = p2o[qrow * 3], qy = p2o[qrow * 3 + 1], qz = p2o[qrow * 3 + 2];
    float qn = __fadd_rn(__fadd_rn(__fmul_rn(qx, qx), __fmul_rn(qy, qy)),
                         __fmul_rn(qz, qz));

    const ull INV = ~0ull;
    ull k1 = INV, k2 = INV, k3 = INV;
#pragma unroll 4
    for (int i = 0; i < 128; ++i) {
        int j = lane + (i << 6);
        ull key = d2key(qx, qy, qz, qn, px[j], py[j], pz[j], j);
        bool b1 = key < k1, b2 = key < k2, b3 = key < k3;
        ull n1 = b1 ? key : k1;
        ull n2 = b1 ? k1 : (b2 ? key : k2);
        ull n3 = b2 ? k2 : (b3 ? key : k3);
        k1 = n1; k2 = n2; k3 = n3;
    }

    int* out = nbr + qrow * KNN;
    for (int r = 0; r < KNN; ++r) {
        ull wk = k1;
#pragma unroll
        for (int off = 1; off < 64; off <<= 1) {
            ull ok = __shfl_xor(wk, off, 64);
            wk = ok < wk ? ok : wk;
        }
        if (lane == 0) out[r] = (int)(unsigned int)(wk & 0xFFFFFFFFull);
        if (k1 == wk) { k1 = k2; k2 = k3; k3 = INV; }
        if (k1 == INV) {   // rare: rebuild top-3 among keys > wk
            for (int i = 0; i < 128; ++i) {
                int j = lane + (i << 6);
                ull key = d2key(qx, qy, qz, qn, px[j], py[j], pz[j], j);
                if (key > wk) {
                    bool b1 = key < k1, b2 = key < k2, b3 = key < k3;
                    ull n1 = b1 ? key : k1;
                    ull n2 = b1 ? k1 : (b2 ? key : k2);
                    ull n3 = b2 ? k2 : (b3 ? key : k3);
                    k1 = n1; k2 = n2; k3 = n3;
                }
            }
        }
    }
}

// ============================================================
// h = x @ W^T : 4 rows per wave (R5 verbatim, passing).
// ============================================================
__global__ __launch_bounds__(256)
void gemm_kernel(const float* __restrict__ x, const float* __restrict__ W,
                 float* __restrict__ h)
{
    const int r0 = blockIdx.x * 16 + (threadIdx.x >> 6) * 4;
    const int cp = threadIdx.x & 63;
    const float4* xp = (const float4*)(x + r0 * CIN);
    const float4* w0 = (const float4*)(W + (cp * 2) * CIN);
    const float4* w1 = (const float4*)(W + (cp * 2 + 1) * CIN);
    float a[4][2];
#pragma unroll
    for (int r = 0; r < 4; ++r) { a[r][0] = 0.f; a[r][1] = 0.f; }
#pragma unroll
    for (int k = 0; k < CIN / 4; ++k) {
        float4 wa = w0[k], wb = w1[k];
#pragma unroll
        for (int r = 0; r < 4; ++r) {
            float4 xv = xp[r * 16 + k];
            a[r][0] = fmaf(xv.x, wa.x, fmaf(xv.y, wa.y, fmaf(xv.z, wa.z, fmaf(xv.w, wa.w, a[r][0]))));
            a[r][1] = fmaf(xv.x, wb.x, fmaf(xv.y, wb.y, fmaf(xv.z, wb.z, fmaf(xv.w, wb.w, a[r][1]))));
        }
    }
#pragma unroll
    for (int r = 0; r < 4; ++r)
        *(float2*)(h + (r0 + r) * COUT + cp * 2) = make_float2(a[r][0], a[r][1]);
}

// ============================================================
// BN stats (R5 verbatim).
// ============================================================
__global__ __launch_bounds__(256)
void stats_kernel(const float* __restrict__ h, float* __restrict__ stats)
{
    __shared__ float4 rs[256], rq[256];
    const int tid  = threadIdx.x;
    const int c4   = (tid & 31) * 4;
    const int rsub = tid >> 5;
    const int rbase = blockIdx.x * 256;
    float4 s = make_float4(0, 0, 0, 0), q = make_float4(0, 0, 0, 0);
    for (int i = 0; i < 32; ++i) {
        int r = rbase + rsub + i * 8;
        float4 v = *(const float4*)(h + r * COUT + c4);
        s.x += v.x; s.y += v.y; s.z += v.z; s.w += v.w;
        q.x = fmaf(v.x, v.x, q.x); q.y = fmaf(v.y, v.y, q.y);
        q.z = fmaf(v.z, v.z, q.z); q.w = fmaf(v.w, v.w, q.w);
    }
    rs[tid] = s; rq[tid] = q;
    __syncthreads();
    if (tid < 32) {
        for (int j = 1; j < 8; ++j) {
            float4 o = rs[tid + 32 * j];
            s.x += o.x; s.y += o.y; s.z += o.z; s.w += o.w;
            float4 oq = rq[tid + 32 * j];
            q.x += oq.x; q.y += oq.y; q.z += oq.z; q.w += oq.w;
        }
        atomicAdd(&stats[c4 + 0], s.x); atomicAdd(&stats[c4 + 1], s.y);
        atomicAdd(&stats[c4 + 2], s.z); atomicAdd(&stats[c4 + 3], s.w);
        atomicAdd(&stats[128 + c4 + 0], q.x); atomicAdd(&stats[128 + c4 + 1], q.y);
        atomicAdd(&stats[128 + c4 + 2], q.z); atomicAdd(&stats[128 + c4 + 3], q.w);
    }
}

__global__ void finalize_kernel(const float* __restrict__ stats,
                                const float* __restrict__ gamma,
                                const float* __restrict__ beta,
                                float* __restrict__ sb)
{
    int c = threadIdx.x;
    float mean = stats[c] * (1.0f / 65536.0f);
    float var  = stats[128 + c] * (1.0f / 65536.0f) - mean * mean;
    float scale = gamma[c] / sqrtf(var + 1e-5f);
    float bias  = beta[c] - mean * scale;
    sb[c] = scale; sb[128 + c] = bias;
}

// ============================================================
// Gather + BN affine + ReLU + max over K (R5 verbatim).
// ============================================================
__global__ __launch_bounds__(256)
void gather_kernel(const float* __restrict__ h, const int* __restrict__ nbr,
                   const float* __restrict__ sb, float* __restrict__ y)
{
    const int wid = threadIdx.x >> 6, lane = threadIdx.x & 63;
    const int t4 = blockIdx.x * 4 + wid;    // == b*2048 + m
    const int b  = t4 >> 11;
    const int c0 = lane * 2;
    float s0 = sb[c0], s1 = sb[c0 + 1];
    float b0 = sb[128 + c0], b1 = sb[128 + c0 + 1];
    const int* nb = nbr + t4 * KNN;
    float a0 = -1e30f, a1 = -1e30f;
#pragma unroll
    for (int k = 0; k < KNN; ++k) {
        int idx = nb[k];
        float2 v = *(const float2*)(h + ((b << 13) + idx) * COUT + c0);
        a0 = fmaxf(a0, fmaf(v.x, s0, b0));
        a1 = fmaxf(a1, fmaf(v.y, s1, b1));
    }
    a0 = fmaxf(a0, 0.0f); a1 = fmaxf(a1, 0.0f);
    *(float2*)(y + t4 * COUT + c0) = make_float2(a0, a1);
}

extern "C" void kernel_launch(void* const* d_in, const int* in_sizes, int n_in,
                              void* d_out, int out_size, void* d_ws, size_t ws_size,
                              hipStream_t stream)
{
    const float* x     = (const float*)d_in[0];
    const float* p1    = (const float*)d_in[1];
    const float* W     = (const float*)d_in[2];
    const float* gamma = (const float*)d_in[3];
    const float* beta  = (const float*)d_in[4];

    float* y  = (float*)d_out;                       // (8,2048,128)
    float* p2 = (float*)d_out + Bb * Mm * COUT;      // (8,2048,3)

    char*  ws    = (char*)d_ws;
    float* h     = (float*)ws;
    int*   nbr   = (int*)(ws + 33619968);
    float* stats = (float*)(ws + 35717120);
    float* sb    = (float*)(ws + 35718144);

    hipMemsetAsync(stats, 0, 1024, stream);
    fps_kernel<<<Bb, 512, 0, stream>>>(p1, p2);
    gemm_kernel<<<NTOT / 16, 256, 0, stream>>>(x, W, h);
    stats_kernel<<<256, 256, 0, stream>>>(h, stats);
    finalize_kernel<<<1, 128, 0, stream>>>(stats, gamma, beta, sb);
    topk_kernel<<<Bb * 128, 1024, 0, stream>>>(p1, p2, nbr);
    gather_kernel<<<Bb * Mm / 4, 256, 0, stream>>>(h, nbr, sb, y);
}

// Round 7
// 2293.228 us; speedup vs baseline: 1.3919x; 1.0156x over previous
//
#include <hip/hip_runtime.h>
#include <stdint.h>

#define Bb   8
#define Nn   8192
#define CIN  64
#define COUT 128
#define Mm   2048
#define KNN  16
#define NTOT (Bb*Nn)   // 65536 rows

typedef unsigned long long ull;
typedef float v2f __attribute__((ext_vector_type(2)));

// ---------------- ws layout (bytes) ----------------
// h        : [0,         33554432)   float 65536x128
// nbr      : [33619968,  35717120)   int   8x2048x16
// stats    : [35717120,  35718144)   float sum[128], sumsq[128]
// sb       : [35718144,  35719168)   float scale[128], bias[128]
//
// LDS RULE (R2-R4 lesson): every workgroup's static LDS must stay
// <= 98,816 B. 131,072+ B silently fails to launch -> poison.

// ============================================================
// Packed f32 add/mul via inline asm: IEEE RN per half, bitwise
// identical to scalar __fadd_rn/__fmul_rn, and immune to FMA
// contraction (compiler can't touch asm). Sub done as a + (-b)
// (sign flip is exact).
// ============================================================
__device__ __forceinline__ v2f pk_add(v2f a, v2f b)
{ v2f d; asm("v_pk_add_f32 %0, %1, %2" : "=v"(d) : "v"(a), "v"(b)); return d; }
__device__ __forceinline__ v2f pk_mul(v2f a, v2f b)
{ v2f d; asm("v_pk_mul_f32 %0, %1, %2" : "=v"(d) : "v"(a), "v"(b)); return d; }

// ============================================================
// Wave64 float-max reduce (R6-proven): 4x DPP row_shr within
// 16-lane rows, then readlane 15/31/47/63 + uniform u32 max
// (valid: distances >= 0, no -0/NaN).
// ============================================================
__device__ __forceinline__ float wave_max16(float x)
{
    int v = __float_as_int(x), t;
    t = __builtin_amdgcn_update_dpp(v, v, 0x111, 0xf, 0xf, false); // row_shr:1
    v = __float_as_int(fmaxf(__int_as_float(v), __int_as_float(t)));
    t = __builtin_amdgcn_update_dpp(v, v, 0x112, 0xf, 0xf, false); // row_shr:2
    v = __float_as_int(fmaxf(__int_as_float(v), __int_as_float(t)));
    t = __builtin_amdgcn_update_dpp(v, v, 0x114, 0xf, 0xf, false); // row_shr:4
    v = __float_as_int(fmaxf(__int_as_float(v), __int_as_float(t)));
    t = __builtin_amdgcn_update_dpp(v, v, 0x118, 0xf, 0xf, false); // row_shr:8
    v = __float_as_int(fmaxf(__int_as_float(v), __int_as_float(t)));
    unsigned r0 = (unsigned)__builtin_amdgcn_readlane(v, 15);
    unsigned r1 = (unsigned)__builtin_amdgcn_readlane(v, 31);
    unsigned r2 = (unsigned)__builtin_amdgcn_readlane(v, 47);
    unsigned r3 = (unsigned)__builtin_amdgcn_readlane(v, 63);
    unsigned m0 = r0 > r1 ? r0 : r1;
    unsigned m1 = r2 > r3 ? r2 : r3;
    unsigned mm = m0 > m1 ? m0 : m1;
    return __uint_as_float(mm);
}

// ============================================================
// FPS: one block per batch, 256 threads (4 waves), 32 pts/thread
// BLOCKED (thread t owns [32t, 32t+32) => lane order == index
// order). Distance math: v_pk add/mul asm, sub as a+(-b) —
// bitwise numpy-identical ((dx^2+dy^2)+dz^2). Two argmax chains
// (even/odd half of each pair), merged with higher-value /
// lower-index tie-break; strict > within a chain keeps lowest i.
// DPP wave max + ballot (lowest lane = lowest index); cross-wave
// u64 key (bits(v)<<32 | ~j) max over 4 keys. ONE double-
// buffered barrier per iteration.
// ============================================================
__global__ __launch_bounds__(256, 1)
void fps_kernel(const float* __restrict__ p1, float* __restrict__ p2out)
{
    __shared__ float px[Nn], py[Nn], pz[Nn];        // 96 KB
    __shared__ alignas(16) ull wkey[2][4];          // + 64 B
    const int b    = blockIdx.x;
    const int tid  = threadIdx.x;
    const int lane = tid & 63, wid = tid >> 6;
    const float* pb = p1 + b * Nn * 3;

    for (int i = tid; i < Nn * 3; i += 256) {
        float v = pb[i];
        int pt = i / 3;
        int c  = i - pt * 3;
        if (c == 0) px[pt] = v; else if (c == 1) py[pt] = v; else pz[pt] = v;
    }
    __syncthreads();

    v2f ppx[16], ppy[16], ppz[16], mind[16];
#pragma unroll
    for (int i = 0; i < 16; ++i) {
        int j0 = tid * 32 + 2 * i;
        ppx[i] = (v2f){px[j0], px[j0 + 1]};
        ppy[i] = (v2f){py[j0], py[j0 + 1]};
        ppz[i] = (v2f){pz[j0], pz[j0 + 1]};
        mind[i] = (v2f){1e10f, 1e10f};
    }

    float lx = px[0], ly = py[0], lz = pz[0];
    if (tid == 0) {
        int o = (b * Mm) * 3;
        p2out[o] = lx; p2out[o + 1] = ly; p2out[o + 2] = lz;
    }

    for (int m = 1; m < Mm; ++m) {
        const int buf = m & 1;
        float nx = -lx, ny = -ly, nz = -lz;     // exact sign flip
        v2f nx2 = (v2f){nx, nx}, ny2 = (v2f){ny, ny}, nz2 = (v2f){nz, nz};
        float bv0 = -1.0f, bv1 = -1.0f; int bj0 = 0, bj1 = 1;
#pragma unroll
        for (int i = 0; i < 16; ++i) {
            v2f dx = pk_add(ppx[i], nx2);       // == ppx - lx, bitwise
            v2f dy = pk_add(ppy[i], ny2);
            v2f dz = pk_add(ppz[i], nz2);
            v2f s  = pk_add(pk_add(pk_mul(dx, dx), pk_mul(dy, dy)),
                            pk_mul(dz, dz));    // ((dx2+dy2)+dz2)
            float m0 = fminf(mind[i].x, s.x);
            float m1 = fminf(mind[i].y, s.y);
            mind[i].x = m0; mind[i].y = m1;
            if (m0 > bv0) { bv0 = m0; bj0 = 2 * i; }
            if (m1 > bv1) { bv1 = m1; bj1 = 2 * i + 1; }
        }
        float bestv; int bestj;
        if (bv1 > bv0 || (bv1 == bv0 && bj1 < bj0)) { bestv = bv1; bestj = bj1; }
        else                                        { bestv = bv0; bestj = bj0; }
        bestj += tid * 32;

        float wv = wave_max16(bestv);
        ull tie = __ballot(bestv == wv);
        int low = __ffsll((long long)tie) - 1;   // lowest lane = lowest index
        if (lane == low) {
            wkey[buf][wid] = ((ull)__float_as_uint(wv) << 32) |
                             (unsigned int)(~(unsigned int)bestj);
        }
        __syncthreads();

        ull k0 = wkey[buf][0], k1 = wkey[buf][1];
        ull k2 = wkey[buf][2], k3 = wkey[buf][3];
        ull k01 = k0 > k1 ? k0 : k1;
        ull k23 = k2 > k3 ? k2 : k3;
        ull fk  = k01 > k23 ? k01 : k23;
        int jw = (int)(~(unsigned int)fk);
        lx = px[jw]; ly = py[jw]; lz = pz[jw];   // broadcast reads
        if (tid == 0) {
            int o = (b * Mm + m) * 3;
            p2out[o] = lx; p2out[o + 1] = ly; p2out[o + 2] = lz;
        }
    }
}

// ============================================================
// kNN top-16 (R5/R6 verbatim, passing): one wave per query,
// 3-plane LDS (98,304 B), per-lane branchless top-3 cache,
// sortable u64 keys tie-break lower index like lax.top_k.
// ============================================================
__device__ __forceinline__ ull d2key(
    float qx, float qy, float qz, float qn, float x, float y, float z, int j)
{
    float dot = __fadd_rn(__fadd_rn(__fmul_rn(qx, x), __fmul_rn(qy, y)),
                          __fmul_rn(qz, z));
    float cn  = __fadd_rn(__fadd_rn(__fmul_rn(x, x), __fmul_rn(y, y)),
                          __fmul_rn(z, z));
    float d2  = __fadd_rn(__fsub_rn(qn, __fadd_rn(dot, dot)), cn);
    unsigned int bits = __float_as_uint(d2);
    unsigned int u = bits ^ (((unsigned int)((int)bits >> 31)) | 0x80000000u);
    return ((ull)u << 32) | (unsigned int)j;
}

__global__ __launch_bounds__(1024, 1)
void topk_kernel(const float* __restrict__ p1, const float* __restrict__ p2o,
                 int* __restrict__ nbr)
{
    __shared__ float px[Nn], py[Nn], pz[Nn];   // 96 KB
    const int tid   = threadIdx.x;
    const int b     = blockIdx.x >> 7;
    const int mbase = (blockIdx.x & 127) << 4;
    const float* pb = p1 + b * Nn * 3;

    for (int i = tid; i < Nn * 3; i += 1024) {
        float v = pb[i];
        int pt = i / 3;
        int c  = i - pt * 3;
        if (c == 0) px[pt] = v; else if (c == 1) py[pt] = v; else pz[pt] = v;
    }
    __syncthreads();

    const int wid = tid >> 6, lane = tid & 63;
    const int qrow = b * Mm + mbase + wid;
    float qx = p2o[qrow * 3], qy = p2o[qrow * 3 + 1], qz = p2o[qrow * 3 + 2];
    float qn = __fadd_rn(__fadd_rn(__fmul_rn(qx, qx), __fmul_rn(qy, qy)),
                         __fmul_rn(qz, qz));

    const ull INV = ~0ull;
    ull k1 = INV, k2 = INV, k3 = INV;
#pragma unroll 4
    for (int i = 0; i < 128; ++i) {
        int j = lane + (i << 6);
        ull key = d2key(qx, qy, qz, qn, px[j], py[j], pz[j], j);
        bool b1 = key < k1, b2 = key < k2, b3 = key < k3;
        ull n1 = b1 ? key : k1;
        ull n2 = b1 ? k1 : (b2 ? key : k2);
        ull n3 = b2 ? k2 : (b3 ? key : k3);
        k1 = n1; k2 = n2; k3 = n3;
    }

    int* out = nbr + qrow * KNN;
    for (int r = 0; r < KNN; ++r) {
        ull wk = k1;
#pragma unroll
        for (int off = 1; off < 64; off <<= 1) {
            ull ok = __shfl_xor(wk, off, 64);
            wk = ok < wk ? ok : wk;
        }
        if (lane == 0) out[r] = (int)(unsigned int)(wk & 0xFFFFFFFFull);
        if (k1 == wk) { k1 = k2; k2 = k3; k3 = INV; }
        if (k1 == INV) {   // rare: rebuild top-3 among keys > wk
            for (int i = 0; i < 128; ++i) {
                int j = lane + (i << 6);
                ull key = d2key(qx, qy, qz, qn, px[j], py[j], pz[j], j);
                if (key > wk) {
                    bool b1 = key < k1, b2 = key < k2, b3 = key < k3;
                    ull n1 = b1 ? key : k1;
                    ull n2 = b1 ? k1 : (b2 ? key : k2);
                    ull n3 = b2 ? k2 : (b3 ? key : k3);
                    k1 = n1; k2 = n2; k3 = n3;
                }
            }
        }
    }
}

// ============================================================
// h = x @ W^T : 4 rows per wave (R5/R6 verbatim, passing).
// ============================================================
__global__ __launch_bounds__(256)
void gemm_kernel(const float* __restrict__ x, const float* __restrict__ W,
                 float* __restrict__ h)
{
    const int r0 = blockIdx.x * 16 + (threadIdx.x >> 6) * 4;
    const int cp = threadIdx.x & 63;
    const float4* xp = (const float4*)(x + r0 * CIN);
    const float4* w0 = (const float4*)(W + (cp * 2) * CIN);
    const float4* w1 = (const float4*)(W + (cp * 2 + 1) * CIN);
    float a[4][2];
#pragma unroll
    for (int r = 0; r < 4; ++r) { a[r][0] = 0.f; a[r][1] = 0.f; }
#pragma unroll
    for (int k = 0; k < CIN / 4; ++k) {
        float4 wa = w0[k], wb = w1[k];
#pragma unroll
        for (int r = 0; r < 4; ++r) {
            float4 xv = xp[r * 16 + k];
            a[r][0] = fmaf(xv.x, wa.x, fmaf(xv.y, wa.y, fmaf(xv.z, wa.z, fmaf(xv.w, wa.w, a[r][0]))));
            a[r][1] = fmaf(xv.x, wb.x, fmaf(xv.y, wb.y, fmaf(xv.z, wb.z, fmaf(xv.w, wb.w, a[r][1]))));
        }
    }
#pragma unroll
    for (int r = 0; r < 4; ++r)
        *(float2*)(h + (r0 + r) * COUT + cp * 2) = make_float2(a[r][0], a[r][1]);
}

// ============================================================
// BN stats (R5/R6 verbatim).
// ============================================================
__global__ __launch_bounds__(256)
void stats_kernel(const float* __restrict__ h, float* __restrict__ stats)
{
    __shared__ float4 rs[256], rq[256];
    const int tid  = threadIdx.x;
    const int c4   = (tid & 31) * 4;
    const int rsub = tid >> 5;
    const int rbase = blockIdx.x * 256;
    float4 s = make_float4(0, 0, 0, 0), q = make_float4(0, 0, 0, 0);
    for (int i = 0; i < 32; ++i) {
        int r = rbase + rsub + i * 8;
        float4 v = *(const float4*)(h + r * COUT + c4);
        s.x += v.x; s.y += v.y; s.z += v.z; s.w += v.w;
        q.x = fmaf(v.x, v.x, q.x); q.y = fmaf(v.y, v.y, q.y);
        q.z = fmaf(v.z, v.z, q.z); q.w = fmaf(v.w, v.w, q.w);
    }
    rs[tid] = s; rq[tid] = q;
    __syncthreads();
    if (tid < 32) {
        for (int j = 1; j < 8; ++j) {
            float4 o = rs[tid + 32 * j];
            s.x += o.x; s.y += o.y; s.z += o.z; s.w += o.w;
            float4 oq = rq[tid + 32 * j];
            q.x += oq.x; q.y += oq.y; q.z += oq.z; q.w += oq.w;
        }
        atomicAdd(&stats[c4 + 0], s.x); atomicAdd(&stats[c4 + 1], s.y);
        atomicAdd(&stats[c4 + 2], s.z); atomicAdd(&stats[c4 + 3], s.w);
        atomicAdd(&stats[128 + c4 + 0], q.x); atomicAdd(&stats[128 + c4 + 1], q.y);
        atomicAdd(&stats[128 + c4 + 2], q.z); atomicAdd(&stats[128 + c4 + 3], q.w);
    }
}

__global__ void finalize_kernel(const float* __restrict__ stats,
                                const float* __restrict__ gamma,
                                const float* __restrict__ beta,
                                float* __restrict__ sb)
{
    int c = threadIdx.x;
    float mean = stats[c] * (1.0f / 65536.0f);
    float var  = stats[128 + c] * (1.0f / 65536.0f) - mean * mean;
    float scale = gamma[c] / sqrtf(var + 1e-5f);
    float bias  = beta[c] - mean * scale;
    sb[c] = scale; sb[128 + c] = bias;
}

// ============================================================
// Gather + BN affine + ReLU + max over K (R5/R6 verbatim).
// ============================================================
__global__ __launch_bounds__(256)
void gather_kernel(const float* __restrict__ h, const int* __restrict__ nbr,
                   const float* __restrict__ sb, float* __restrict__ y)
{
    const int wid = threadIdx.x >> 6, lane = threadIdx.x & 63;
    const int t4 = blockIdx.x * 4 + wid;    // == b*2048 + m
    const int b  = t4 >> 11;
    const int c0 = lane * 2;
    float s0 = sb[c0], s1 = sb[c0 + 1];
    float b0 = sb[128 + c0], b1 = sb[128 + c0 + 1];
    const int* nb = nbr + t4 * KNN;
    float a0 = -1e30f, a1 = -1e30f;
#pragma unroll
    for (int k = 0; k < KNN; ++k) {
        int idx = nb[k];
        float2 v = *(const float2*)(h + ((b << 13) + idx) * COUT + c0);
        a0 = fmaxf(a0, fmaf(v.x, s0, b0));
        a1 = fmaxf(a1, fmaf(v.y, s1, b1));
    }
    a0 = fmaxf(a0, 0.0f); a1 = fmaxf(a1, 0.0f);
    *(float2*)(y + t4 * COUT + c0) = make_float2(a0, a1);
}

extern "C" void kernel_launch(void* const* d_in, const int* in_sizes, int n_in,
                              void* d_out, int out_size, void* d_ws, size_t ws_size,
                              hipStream_t stream)
{
    const float* x     = (const float*)d_in[0];
    const float* p1    = (const float*)d_in[1];
    const float* W     = (const float*)d_in[2];
    const float* gamma = (const float*)d_in[3];
    const float* beta  = (const float*)d_in[4];

    float* y  = (float*)d_out;                       // (8,2048,128)
    float* p2 = (float*)d_out + Bb * Mm * COUT;      // (8,2048,3)

    char*  ws    = (char*)d_ws;
    float* h     = (float*)ws;
    int*   nbr   = (int*)(ws + 33619968);
    float* stats = (float*)(ws + 35717120);
    float* sb    = (float*)(ws + 35718144);

    hipMemsetAsync(stats, 0, 1024, stream);
    fps_kernel<<<Bb, 256, 0, stream>>>(p1, p2);
    gemm_kernel<<<NTOT / 16, 256, 0, stream>>>(x, W, h);
    stats_kernel<<<256, 256, 0, stream>>>(h, stats);
    finalize_kernel<<<1, 128, 0, stream>>>(stats, gamma, beta, sb);
    topk_kernel<<<Bb * 128, 1024, 0, stream>>>(p1, p2, nbr);
    gather_kernel<<<Bb * Mm / 4, 256, 0, stream>>>(h, nbr, sb, y);
}